// Round 8
// baseline (708.704 us; speedup 1.0000x reference)
//
#include <hip/hip_runtime.h>
#include <hip/hip_fp16.h>
#include <math.h>

#define N_ENT  150000
#define N_USR  60000
#define CDIM   64
#define NE     1000000
#define NNZV   1000000
#define NREL9  9                        // weight rows incl. np-wrap row 8
#define NTOT   (2 * N_ENT + N_USR)      // 360000 concatenated segment counters
#define TOTAL_ITEMS (NE + 2 * NNZV)     // 3000000 (scan sentinel)
#define SCAN_B ((NTOT + 1023) / 1024)   // 352 scan blocks

#define NXCD   8
#define H_PER  (N_ENT / NXCD)           // 18750 heads/cols per role
#define R_PER  (N_USR / NXCD)           // 7500 rows per role
#define EPB    2048                     // edges per chunk
#define NCHUNK ((NE + EPB - 1) / EPB)   // 489
#define HISTB  (NCHUNK * NXCD)          // 3912 hist blocks (must start at 0!)

#define EG (N_ENT / 4)                  // 37500 entity blocks (4 waves each)
#define UG (N_USR / 4)                  // 15000 user blocks
#define UCVT ((N_USR * CDIM / 2 + 255) / 256)  // 7500 usr-cvt blocks

// ---- DPP wave reductions (VALU pipe, no LDS) ----------------------------
// rocPRIM warp_reduce_dpp pattern. bound_ctrl=true: OOR lanes contribute 0 —
// exact for sum, and for max of non-negative values.
template <int CTRL>
__device__ __forceinline__ float dpp_addf(float v) {
    int iv = __float_as_int(v);
    int x = __builtin_amdgcn_update_dpp(iv, iv, CTRL, 0xF, 0xF, true);
    return v + __int_as_float(x);
}
template <int CTRL>
__device__ __forceinline__ float dpp_maxf(float v) {
    int iv = __float_as_int(v);
    int x = __builtin_amdgcn_update_dpp(iv, iv, CTRL, 0xF, 0xF, true);
    return fmaxf(v, __int_as_float(x));
}
__device__ __forceinline__ float wave_sum(float v) {
    v = dpp_addf<0x111>(v);   // row_shr:1
    v = dpp_addf<0x112>(v);   // row_shr:2
    v = dpp_addf<0x114>(v);   // row_shr:4
    v = dpp_addf<0x118>(v);   // row_shr:8
    v = dpp_addf<0x142>(v);   // row_bcast:15
    v = dpp_addf<0x143>(v);   // row_bcast:31
    return __int_as_float(__builtin_amdgcn_readlane(__float_as_int(v), 63));
}
__device__ __forceinline__ float wave_max(float v) {
    v = dpp_maxf<0x111>(v);
    v = dpp_maxf<0x112>(v);
    v = dpp_maxf<0x114>(v);
    v = dpp_maxf<0x118>(v);
    v = dpp_maxf<0x142>(v);
    v = dpp_maxf<0x143>(v);
    return __int_as_float(__builtin_amdgcn_readlane(__float_as_int(v), 63));
}

// Uniform-lane broadcast: readlane result is uniform to the compiler, so
// pointers derived from it become SGPR bases (saddr loads, SALU addr math).
// Lane index may be a uniform runtime value (SGPR).
__device__ __forceinline__ int   bcast_i(int v, int l)   { return __builtin_amdgcn_readlane(v, l); }
__device__ __forceinline__ float bcast_f(float v, int l) { return __int_as_float(__builtin_amdgcn_readlane(__float_as_int(v), l)); }

// Block-wide exclusive scan (blockDim multiple of 64, <=1024). lds: >=16 ints.
__device__ __forceinline__ int block_excl_scan(int v, int* lds) {
    int lane = threadIdx.x & 63, wid = threadIdx.x >> 6;
    int incl = v;
#pragma unroll
    for (int o = 1; o < 64; o <<= 1) {
        int t = __shfl_up(incl, o, 64);
        if (lane >= o) incl += t;
    }
    if (lane == 63) lds[wid] = incl;
    __syncthreads();
    int nw = blockDim.x >> 6;
    if ((int)threadIdx.x < nw) {
        int s = lds[threadIdx.x];
        int si = s;
        for (int o = 1; o < nw; o <<= 1) {
            int t = __shfl_up(si, o, 64);
            if ((int)threadIdx.x >= o) si += t;
        }
        lds[threadIdx.x] = si - s;  // exclusive offset for this wave
    }
    __syncthreads();
    return incl - v + lds[wid];
}

// ---- Fused front-end: blocks [0,HISTB) role-split histogram (XCD-local
// atomics — blockIdx&7 = role = XCD, so hist MUST occupy block ids from 0);
// [HISTB, HISTB+EG) entity fp16 cvt + sq table; rest usr fp16 cvt.
// hist and prep are data-independent; fusing hides prep's ~20us behind hist.
__global__ __launch_bounds__(256) void k_histprep(
    const int* __restrict__ head, const int* __restrict__ cols,
    const int* __restrict__ rows, int* __restrict__ cnt,
    const float* __restrict__ ent, const float* __restrict__ usr,
    const float* __restrict__ wt,
    __half* __restrict__ ent16, __half* __restrict__ usr16,
    float* __restrict__ sq)
{
    int b = blockIdx.x;
    if (b < HISTB) {
        int role  = b & (NXCD - 1);
        int chunk = b >> 3;
        int h0 = role * H_PER, h1 = h0 + H_PER;
        int r0 = role * R_PER, r1 = r0 + R_PER;
        int base = chunk * EPB;
        int end  = min(base + EPB, NE);
        for (int i = base + (int)threadIdx.x; i < end; i += 256) {
            int h = head[i];
            int c = cols[i];
            int r = rows[i];
            if (h >= h0 && h < h1) atomicAdd(cnt + h, 1);
            if (c >= h0 && c < h1) atomicAdd(cnt + N_ENT + c, 1);
            if (r >= r0 && r < r1) atomicAdd(cnt + 2 * N_ENT + r, 1);
        }
    } else if (b < HISTB + EG) {
        int e = ((b - HISTB) * 256 + (int)threadIdx.x) >> 6;
        int lane = threadIdx.x & 63;
        float own = ent[(e << 6) + lane];
        ent16[(e << 6) + lane] = __float2half(own);
        float o2 = own * own;
        float mine = 0.f;
#pragma unroll
        for (int rt = 0; rt < NREL9; ++rt) {
            float r = wt[(rt << 6) + lane];
            float s = wave_sum(o2 * r * r);
            if (lane == rt) mine = s;
        }
        if (lane < NREL9) sq[e * NREL9 + lane] = mine;
    } else {
        int i = (b - HISTB - EG) * 256 + (int)threadIdx.x;   // float2 index
        if (i < N_USR * CDIM / 2) {
            float2 v = ((const float2*)usr)[i];
            ((__half2*)usr16)[i] = __floats2half2_rn(v.x, v.y);
        }
    }
}

__global__ __launch_bounds__(1024) void k_bsum(
    const int* __restrict__ cnt, int* __restrict__ bsum)
{
    __shared__ int lds[16];
    int i = blockIdx.x * 1024 + threadIdx.x;
    float v = (i < NTOT) ? (float)cnt[i] : 0.f;
    float s = wave_sum(v);                 // exact: block total <= 3M < 2^24
    int lane = threadIdx.x & 63, wid = threadIdx.x >> 6;
    if (lane == 0) lds[wid] = (int)s;
    __syncthreads();
    if (threadIdx.x == 0) {
        int t = 0;
        for (int k = 0; k < 16; ++k) t += lds[k];
        bsum[blockIdx.x] = t;
    }
}

__global__ __launch_bounds__(512) void k_scan_small(int* __restrict__ bsum)
{
    __shared__ int lds[16];
    int i = threadIdx.x;
    int v = (i < SCAN_B) ? bsum[i] : 0;
    int e = block_excl_scan(v, lds);
    if (i < SCAN_B) bsum[i] = e;
}

// start[i] = exclusive prefix (immutable); start[NTOT] = sentinel.
__global__ __launch_bounds__(1024) void k_scan_apply(
    const int* __restrict__ cnt, const int* __restrict__ bsum,
    int* __restrict__ start, int* __restrict__ cursor)
{
    __shared__ int lds[16];
    int i = blockIdx.x * 1024 + threadIdx.x;
    int v = (i < NTOT) ? cnt[i] : 0;
    int e = block_excl_scan(v, lds) + bsum[blockIdx.x];
    if (i < NTOT) { start[i] = e; cursor[i] = e; }
    else if (i == NTOT) { start[i] = TOTAL_ITEMS; }
}

// Scatter payloads into segment-sorted arrays. XCD-localized (R0). Payload
// fields loaded CONDITIONALLY (tail/etype 1/8 of iters, vals ~1/4).
__global__ __launch_bounds__(256) void k_scatter(
    const int* __restrict__ head, const int* __restrict__ tail,
    const int* __restrict__ etype,
    const int* __restrict__ rows, const int* __restrict__ cols,
    const float* __restrict__ vals,
    int* __restrict__ cursor,
    int* __restrict__ pk_h,                  // tail | rt<<18, sorted by head
    int2* __restrict__ rc,                   // (row, valbits) sorted by col
    int2* __restrict__ cv)                   // (col, valbits) sorted by row
{
    int role  = blockIdx.x & (NXCD - 1);
    int chunk = blockIdx.x >> 3;
    int h0 = role * H_PER, h1 = h0 + H_PER;
    int r0 = role * R_PER, r1 = r0 + R_PER;
    int base = chunk * EPB;
    int end  = min(base + EPB, NE);
    for (int i = base + (int)threadIdx.x; i < end; i += 256) {
        int h = head[i];
        int c = cols[i];
        int r = rows[i];
        if (h >= h0 && h < h1) {
            int rt = etype[i] - 1;
            if (rt < 0) rt = 8;              // weight[-1] -> row 8 (np wrap)
            int p = atomicAdd(cursor + h, 1);
            if ((unsigned)p < (unsigned)NE) pk_h[p] = tail[i] | (rt << 18);
        }
        if (c >= h0 && c < h1) {
            int vb = __float_as_int(vals[i]);
            int p = atomicAdd(cursor + N_ENT + c, 1) - NE;
            if ((unsigned)p < (unsigned)NNZV) rc[p] = make_int2(r, vb);
        }
        if (r >= r0 && r < r1) {
            int vb = __float_as_int(vals[i]);
            int p = atomicAdd(cursor + 2 * N_ENT + r, 1) - 2 * NE;
            if ((unsigned)p < (unsigned)NNZV) cv[p] = make_int2(c, vb);
        }
    }
}

// ---- Fused per-hop kernel: blocks [0,EG) = entity role, rest = user. ----
// Gather loops use MASKED-PAD batching (always 8 gathers in flight, clamped
// index + wk=0 for kk>=cnt) + 2 alternating accumulators: short segments
// (avg degree ~7) no longer hit a serial load->FMA tail. Mask is a uniform
// s_cselect — no per-edge branch (R6 lesson).
template <bool FIRST, bool LAST>
__global__ __launch_bounds__(256) void k_hop(
    const __half* __restrict__ ent16_cur, const __half* __restrict__ usr16_cur,
    const float* __restrict__ ent_res_base, const float* __restrict__ usr_res_base,
    const float* __restrict__ wt, const int* __restrict__ start,
    const int* __restrict__ pk_h, const float* __restrict__ sq_in,
    const int2* __restrict__ rc, const int2* __restrict__ cv,
    __half* __restrict__ ent16_next, __half* __restrict__ usr16_next,
    float* __restrict__ sq_out,
    float* __restrict__ out_ent, float* __restrict__ out_usr)
{
    int lane = threadIdx.x & 63;
    int b = blockIdx.x;

    if (b < EG) {
        // ================= entity role: one wave per entity ==============
        int e = (b * 256 + (int)threadIdx.x) >> 6;

        // --- softmax-weighted neighbor aggregation, edges head == e ---
        int s1 = min(start[e + 1], NE);
        int s0 = min(start[e], s1);
        float m = 0.f, l = 0.f;               // att >= 0 so m=0 init exact
        float accA = 0.f, accB = 0.f;
        for (int base = s0; base < s1; base += 64) {
            int j = base + lane;
            int cnt = min(64, s1 - base);
            int pk = 0; float att = 0.f;
            if (j < s1) {                      // coalesced descriptor load
                pk = pk_h[j];
                int t = pk & 0x3FFFF, rt = (pk >> 18) & 15;
                att = sq_in[e * NREL9 + rt] * sq_in[t * NREL9 + rt];
            }
            float mn = fmaxf(m, wave_max(att));
            float scale = __expf(m - mn);      // first chunk multiplies zeros
            float p = (j < s1) ? __expf(att - mn) : 0.f;
            l = l * scale + wave_sum(p);
            accA *= scale; accB *= scale;
            m = mn;
            for (int k = 0; k < cnt; k += 8) {
#pragma unroll
                for (int q = 0; q < 8; ++q) {
                    int kk = k + q;
                    int sel = (kk < cnt) ? kk : 0;       // uniform clamp
                    int pkk = bcast_i(pk, sel);
                    float wk = (kk < cnt) ? bcast_f(p, sel) : 0.f;
                    const __half* tp = ent16_cur + ((pkk & 0x3FFFF) << 6);
                    const float*  wp = wt + (((pkk >> 18) & 15) << 6);
                    float prod = wk * __half2float(tp[lane]) * wp[lane];
                    if (q & 1) accB += prod; else accA += prod;
                }
            }
        }
        float acc = accA + accB;
        float agg = (l > 0.f) ? acc / l : 0.f;

        // --- + interact_mat^T @ user_emb  (nnz with col == e) ---
        int c1 = min(start[N_ENT + e + 1] - NE, NNZV);
        int c0 = max(min(start[N_ENT + e] - NE, c1), 0);
        float agA = 0.f, agB = 0.f;
        for (int base = c0; base < c1; base += 64) {
            int j = base + lane;
            int cnt = min(64, c1 - base);
            int rr = 0; float vv = 0.f;
            if (j < c1) { int2 q = rc[j]; rr = q.x; vv = __int_as_float(q.y); }
            for (int k = 0; k < cnt; k += 8) {
#pragma unroll
                for (int q = 0; q < 8; ++q) {
                    int kk = k + q;
                    int sel = (kk < cnt) ? kk : 0;
                    int u = bcast_i(rr, sel);
                    float v = (kk < cnt) ? bcast_f(vv, sel) : 0.f;
                    float prod = v * __half2float(usr16_cur[(u << 6) + lane]);
                    if (q & 1) agB += prod; else agA += prod;
                }
            }
        }
        agg += agA + agB;

        // --- normalize + residual (+ next-hop sq from registers) ---
        float s = wave_sum(agg * agg);
        float y = agg / fmaxf(sqrtf(s), 1e-12f);
        int oi = (e << 6) + lane;
        if (!LAST) {
            ent16_next[oi] = __float2half(y);
            float y2 = y * y;
            float mine = 0.f;
#pragma unroll
            for (int rt = 0; rt < NREL9; ++rt) {
                float r = wt[(rt << 6) + lane];
                float sv = wave_sum(y2 * r * r);
                if (lane == rt) mine = sv;
            }
            if (lane < NREL9) sq_out[e * NREL9 + lane] = mine;
        }
        if (FIRST) out_ent[oi] = ent_res_base[oi] + y;
        else       out_ent[oi] += y;
    } else {
        // ================= user role: one wave per user ==================
        int u = ((b - EG) * 256 + (int)threadIdx.x) >> 6;
        int s1 = min(start[2 * N_ENT + u + 1] - 2 * NE, NNZV);
        int s0 = max(min(start[2 * N_ENT + u] - 2 * NE, s1), 0);
        float acA = 0.f, acB = 0.f;
        for (int base = s0; base < s1; base += 64) {
            int j = base + lane;
            int cnt = min(64, s1 - base);
            int cc = 0; float vv = 0.f;
            if (j < s1) { int2 q = cv[j]; cc = q.x; vv = __int_as_float(q.y); }
            for (int k = 0; k < cnt; k += 8) {
#pragma unroll
                for (int q = 0; q < 8; ++q) {
                    int kk = k + q;
                    int sel = (kk < cnt) ? kk : 0;
                    int c = bcast_i(cc, sel);
                    float v = (kk < cnt) ? bcast_f(vv, sel) : 0.f;
                    float prod = v * __half2float(ent16_cur[(c << 6) + lane]);
                    if (q & 1) acB += prod; else acA += prod;
                }
            }
        }
        float acc = acA + acB;
        float s = wave_sum(acc * acc);
        float y = acc / fmaxf(sqrtf(s), 1e-12f);
        int oi = (u << 6) + lane;
        if (!LAST) usr16_next[oi] = __float2half(y);
        if (FIRST) out_usr[oi] = usr_res_base[oi] + y;
        else       out_usr[oi] += y;
    }
}

extern "C" void kernel_launch(void* const* d_in, const int* in_sizes, int n_in,
                              void* d_out, int out_size, void* d_ws, size_t ws_size,
                              hipStream_t stream)
{
    const float* user_emb   = (const float*)d_in[0];
    const float* entity_emb = (const float*)d_in[1];
    const float* wt         = (const float*)d_in[2];
    const float* inter_vals = (const float*)d_in[3];
    const int*   edge_index = (const int*)d_in[4];
    const int*   etype      = (const int*)d_in[5];
    const int*   inter_rows = (const int*)d_in[6];
    const int*   inter_cols = (const int*)d_in[7];
    const int* head  = edge_index;
    const int* tailp = edge_index + NE;

    // Workspace layout (~89 MB); every buffer written before read each call.
    __half* ent16_a = (__half*)d_ws;                         // N_ENT*64 halves
    __half* ent16_b = ent16_a + (size_t)N_ENT * CDIM;        // N_ENT*64
    __half* usr16_a = ent16_b + (size_t)N_ENT * CDIM;        // N_USR*64
    __half* usr16_b = usr16_a + (size_t)N_USR * CDIM;        // N_USR*64
    int2*  rc     = (int2*)(usr16_b + (size_t)N_USR * CDIM); // NNZ
    int2*  cv     = rc + NNZV;                               // NNZ
    int*   pk_h   = (int*)(cv + NNZV);                       // NE
    int*   cnt    = pk_h + NE;                               // NTOT
    int*   start  = cnt + NTOT;                              // NTOT+1
    int*   cursor = start + NTOT + 1;                        // NTOT+1
    int*   bsum   = cursor + NTOT + 1;                       // SCAN_B
    float* sq_a   = (float*)(bsum + SCAN_B);                 // N_ENT*9
    float* sq_b   = sq_a + (size_t)N_ENT * NREL9;            // N_ENT*9

    float* out_ent = (float*)d_out;
    float* out_usr = out_ent + (size_t)N_ENT * CDIM;

    // ---- CSR build + hop-1 prep (hist blocks FIRST for role mapping) ----
    hipMemsetAsync(cnt, 0, (size_t)NTOT * sizeof(int), stream);
    k_histprep<<<HISTB + EG + UCVT, 256, 0, stream>>>(
        head, inter_cols, inter_rows, cnt,
        entity_emb, user_emb, wt, ent16_a, usr16_a, sq_a);
    k_bsum<<<SCAN_B, 1024, 0, stream>>>(cnt, bsum);
    k_scan_small<<<1, 512, 0, stream>>>(bsum);
    k_scan_apply<<<SCAN_B, 1024, 0, stream>>>(cnt, bsum, start, cursor);
    k_scatter<<<NCHUNK * NXCD, 256, 0, stream>>>(
        head, tailp, etype, inter_rows, inter_cols, inter_vals,
        cursor, pk_h, rc, cv);

    // ---- hop 1: gather fp16_a; write fp16_b + sq_b; out = input + y1 ----
    k_hop<true, false><<<EG + UG, 256, 0, stream>>>(
        ent16_a, usr16_a, entity_emb, user_emb, wt, start, pk_h, sq_a, rc, cv,
        ent16_b, usr16_b, sq_b, out_ent, out_usr);

    // ---- hop 2: gather fp16_b; out += y2 ----
    k_hop<false, true><<<EG + UG, 256, 0, stream>>>(
        ent16_b, usr16_b, nullptr, nullptr, wt, start, pk_h, sq_b, rc, cv,
        nullptr, nullptr, nullptr, out_ent, out_usr);
}

// Round 9
// 673.360 us; speedup vs baseline: 1.0525x; 1.0525x over previous
//
#include <hip/hip_runtime.h>
#include <hip/hip_fp16.h>
#include <math.h>

#define N_ENT  150000
#define N_USR  60000
#define CDIM   64
#define NE     1000000
#define NNZV   1000000
#define NREL9  9                        // weight rows incl. np-wrap row 8
#define NTOT   (2 * N_ENT + N_USR)      // 360000 concatenated segment counters
#define TOTAL_ITEMS (NE + 2 * NNZV)     // 3000000 (scan sentinel)
#define SCAN_B ((NTOT + 1023) / 1024)   // 352 scan blocks

#define NXCD   8
#define H_PER  (N_ENT / NXCD)           // 18750 heads/cols per role
#define R_PER  (N_USR / NXCD)           // 7500 rows per role
#define EPB    2048                     // edges per chunk
#define NCHUNK ((NE + EPB - 1) / EPB)   // 489
#define HISTB  (NCHUNK * NXCD)          // 3912 hist blocks (must start at 0!)

#define EG (N_ENT / 4)                  // 37500 entity blocks (4 waves each)
#define UG (N_USR / 4)                  // 15000 user blocks
#define UCVT ((N_USR * CDIM / 2 + 255) / 256)  // 7500 usr-cvt blocks

// ---- DPP wave reductions (VALU pipe, no LDS) ----------------------------
// rocPRIM warp_reduce_dpp pattern. bound_ctrl=true: OOR lanes contribute 0 —
// exact for sum, and for max of non-negative values.
template <int CTRL>
__device__ __forceinline__ float dpp_addf(float v) {
    int iv = __float_as_int(v);
    int x = __builtin_amdgcn_update_dpp(iv, iv, CTRL, 0xF, 0xF, true);
    return v + __int_as_float(x);
}
template <int CTRL>
__device__ __forceinline__ float dpp_maxf(float v) {
    int iv = __float_as_int(v);
    int x = __builtin_amdgcn_update_dpp(iv, iv, CTRL, 0xF, 0xF, true);
    return fmaxf(v, __int_as_float(x));
}
__device__ __forceinline__ float wave_sum(float v) {
    v = dpp_addf<0x111>(v);   // row_shr:1
    v = dpp_addf<0x112>(v);   // row_shr:2
    v = dpp_addf<0x114>(v);   // row_shr:4
    v = dpp_addf<0x118>(v);   // row_shr:8
    v = dpp_addf<0x142>(v);   // row_bcast:15
    v = dpp_addf<0x143>(v);   // row_bcast:31
    return __int_as_float(__builtin_amdgcn_readlane(__float_as_int(v), 63));
}
__device__ __forceinline__ float wave_max(float v) {
    v = dpp_maxf<0x111>(v);
    v = dpp_maxf<0x112>(v);
    v = dpp_maxf<0x114>(v);
    v = dpp_maxf<0x118>(v);
    v = dpp_maxf<0x142>(v);
    v = dpp_maxf<0x143>(v);
    return __int_as_float(__builtin_amdgcn_readlane(__float_as_int(v), 63));
}

__device__ __forceinline__ float bcast_f(float v, int l) { return __int_as_float(__builtin_amdgcn_readlane(__float_as_int(v), l)); }

// Block-wide exclusive scan (blockDim multiple of 64, <=1024). lds: >=16 ints.
__device__ __forceinline__ int block_excl_scan(int v, int* lds) {
    int lane = threadIdx.x & 63, wid = threadIdx.x >> 6;
    int incl = v;
#pragma unroll
    for (int o = 1; o < 64; o <<= 1) {
        int t = __shfl_up(incl, o, 64);
        if (lane >= o) incl += t;
    }
    if (lane == 63) lds[wid] = incl;
    __syncthreads();
    int nw = blockDim.x >> 6;
    if ((int)threadIdx.x < nw) {
        int s = lds[threadIdx.x];
        int si = s;
        for (int o = 1; o < nw; o <<= 1) {
            int t = __shfl_up(si, o, 64);
            if ((int)threadIdx.x >= o) si += t;
        }
        lds[threadIdx.x] = si - s;  // exclusive offset for this wave
    }
    __syncthreads();
    return incl - v + lds[wid];
}

// ---- Fused front-end: blocks [0,HISTB) role-split histogram (XCD-local
// atomics — blockIdx&7 = role, hist MUST occupy block ids from 0);
// [HISTB, HISTB+EG) entity fp16 cvt + sq table; rest usr fp16 cvt.
__global__ __launch_bounds__(256) void k_histprep(
    const int* __restrict__ head, const int* __restrict__ cols,
    const int* __restrict__ rows, int* __restrict__ cnt,
    const float* __restrict__ ent, const float* __restrict__ usr,
    const float* __restrict__ wt,
    __half* __restrict__ ent16, __half* __restrict__ usr16,
    float* __restrict__ sq)
{
    int b = blockIdx.x;
    if (b < HISTB) {
        int role  = b & (NXCD - 1);
        int chunk = b >> 3;
        int h0 = role * H_PER, h1 = h0 + H_PER;
        int r0 = role * R_PER, r1 = r0 + R_PER;
        int base = chunk * EPB;
        int end  = min(base + EPB, NE);
        for (int i = base + (int)threadIdx.x; i < end; i += 256) {
            int h = head[i];
            int c = cols[i];
            int r = rows[i];
            if (h >= h0 && h < h1) atomicAdd(cnt + h, 1);
            if (c >= h0 && c < h1) atomicAdd(cnt + N_ENT + c, 1);
            if (r >= r0 && r < r1) atomicAdd(cnt + 2 * N_ENT + r, 1);
        }
    } else if (b < HISTB + EG) {
        int e = ((b - HISTB) * 256 + (int)threadIdx.x) >> 6;
        int lane = threadIdx.x & 63;
        float own = ent[(e << 6) + lane];
        ent16[(e << 6) + lane] = __float2half(own);
        float o2 = own * own;
        float mine = 0.f;
#pragma unroll
        for (int rt = 0; rt < NREL9; ++rt) {
            float r = wt[(rt << 6) + lane];
            float s = wave_sum(o2 * r * r);
            if (lane == rt) mine = s;
        }
        if (lane < NREL9) sq[e * NREL9 + lane] = mine;
    } else {
        int i = (b - HISTB - EG) * 256 + (int)threadIdx.x;   // float2 index
        if (i < N_USR * CDIM / 2) {
            float2 v = ((const float2*)usr)[i];
            ((__half2*)usr16)[i] = __floats2half2_rn(v.x, v.y);
        }
    }
}

__global__ __launch_bounds__(1024) void k_bsum(
    const int* __restrict__ cnt, int* __restrict__ bsum)
{
    __shared__ int lds[16];
    int i = blockIdx.x * 1024 + threadIdx.x;
    float v = (i < NTOT) ? (float)cnt[i] : 0.f;
    float s = wave_sum(v);                 // exact: block total <= 3M < 2^24
    int lane = threadIdx.x & 63, wid = threadIdx.x >> 6;
    if (lane == 0) lds[wid] = (int)s;
    __syncthreads();
    if (threadIdx.x == 0) {
        int t = 0;
        for (int k = 0; k < 16; ++k) t += lds[k];
        bsum[blockIdx.x] = t;
    }
}

__global__ __launch_bounds__(512) void k_scan_small(int* __restrict__ bsum)
{
    __shared__ int lds[16];
    int i = threadIdx.x;
    int v = (i < SCAN_B) ? bsum[i] : 0;
    int e = block_excl_scan(v, lds);
    if (i < SCAN_B) bsum[i] = e;
}

// start[i] = exclusive prefix (immutable); start[NTOT] = sentinel.
__global__ __launch_bounds__(1024) void k_scan_apply(
    const int* __restrict__ cnt, const int* __restrict__ bsum,
    int* __restrict__ start, int* __restrict__ cursor)
{
    __shared__ int lds[16];
    int i = blockIdx.x * 1024 + threadIdx.x;
    int v = (i < NTOT) ? cnt[i] : 0;
    int e = block_excl_scan(v, lds) + bsum[blockIdx.x];
    if (i < NTOT) { start[i] = e; cursor[i] = e; }
    else if (i == NTOT) { start[i] = TOTAL_ITEMS; }
}

// Scatter payloads into segment-sorted arrays. XCD-localized (R0). Payload
// fields loaded CONDITIONALLY (tail/etype 1/8 of iters, vals ~1/4).
__global__ __launch_bounds__(256) void k_scatter(
    const int* __restrict__ head, const int* __restrict__ tail,
    const int* __restrict__ etype,
    const int* __restrict__ rows, const int* __restrict__ cols,
    const float* __restrict__ vals,
    int* __restrict__ cursor,
    int* __restrict__ pk_h,                  // tail | rt<<18, sorted by head
    int2* __restrict__ rc,                   // (row, valbits) sorted by col
    int2* __restrict__ cv)                   // (col, valbits) sorted by row
{
    int role  = blockIdx.x & (NXCD - 1);
    int chunk = blockIdx.x >> 3;
    int h0 = role * H_PER, h1 = h0 + H_PER;
    int r0 = role * R_PER, r1 = r0 + R_PER;
    int base = chunk * EPB;
    int end  = min(base + EPB, NE);
    for (int i = base + (int)threadIdx.x; i < end; i += 256) {
        int h = head[i];
        int c = cols[i];
        int r = rows[i];
        if (h >= h0 && h < h1) {
            int rt = etype[i] - 1;
            if (rt < 0) rt = 8;              // weight[-1] -> row 8 (np wrap)
            int p = atomicAdd(cursor + h, 1);
            if ((unsigned)p < (unsigned)NE) pk_h[p] = tail[i] | (rt << 18);
        }
        if (c >= h0 && c < h1) {
            int vb = __float_as_int(vals[i]);
            int p = atomicAdd(cursor + N_ENT + c, 1) - NE;
            if ((unsigned)p < (unsigned)NNZV) rc[p] = make_int2(r, vb);
        }
        if (r >= r0 && r < r1) {
            int vb = __float_as_int(vals[i]);
            int p = atomicAdd(cursor + 2 * N_ENT + r, 1) - 2 * NE;
            if ((unsigned)p < (unsigned)NNZV) cv[p] = make_int2(c, vb);
        }
    }
}

// ---- Fused per-hop kernel: blocks [0,EG) = entity role, rest = user. ----
// e/u hoisted to SGPR via readfirstlane -> segment bounds and descriptor
// addresses are provably wave-uniform -> rc/cv/pk_h broadcast reads become
// SMEM s_load (no VALU, no per-lane staging, no readlanes). The pk gather
// loop keeps exactly ONE readlane per edge (wk, computed per-lane by exp).
template <bool FIRST, bool LAST>
__global__ __launch_bounds__(256) void k_hop(
    const __half* __restrict__ ent16_cur, const __half* __restrict__ usr16_cur,
    const float* __restrict__ ent_res_base, const float* __restrict__ usr_res_base,
    const float* __restrict__ wt, const int* __restrict__ start,
    const int* __restrict__ pk_h, const float* __restrict__ sq_in,
    const int2* __restrict__ rc, const int2* __restrict__ cv,
    __half* __restrict__ ent16_next, __half* __restrict__ usr16_next,
    float* __restrict__ sq_out,
    float* __restrict__ out_ent, float* __restrict__ out_usr)
{
    int lane = threadIdx.x & 63;
    int b = blockIdx.x;

    if (b < EG) {
        // ================= entity role: one wave per entity ==============
        int e = __builtin_amdgcn_readfirstlane((b * 256 + (int)threadIdx.x) >> 6);

        // --- softmax-weighted neighbor aggregation, edges head == e ---
        int s1 = min(start[e + 1], NE);
        int s0 = min(start[e], s1);
        float m = 0.f, l = 0.f, acc = 0.f;    // att >= 0 so m=0 init exact
        for (int base = s0; base < s1; base += 64) {
            int j = base + lane;
            int cnt = min(64, s1 - base);
            float att = 0.f;
            if (j < s1) {                      // coalesced descriptor load
                int pk = pk_h[j];
                int t = pk & 0x3FFFF, rt = (pk >> 18) & 15;
                att = sq_in[e * NREL9 + rt] * sq_in[t * NREL9 + rt];
            }
            float mn = fmaxf(m, wave_max(att));
            float scale = __expf(m - mn);      // first chunk multiplies zeros
            float p = (j < s1) ? __expf(att - mn) : 0.f;
            l = l * scale + wave_sum(p);
            acc *= scale;
            m = mn;
            int k = 0;
            for (; k + 4 <= cnt; k += 4) {     // 4 independent gathers in flight
#pragma unroll
                for (int q = 0; q < 4; ++q) {
                    int pkk = pk_h[base + k + q];          // uniform -> s_load
                    float wk = bcast_f(p, k + q);
                    const __half* tp = ent16_cur + ((pkk & 0x3FFFF) << 6);
                    const float*  wp = wt + (((pkk >> 18) & 15) << 6);
                    acc += wk * __half2float(tp[lane]) * wp[lane];
                }
            }
            for (; k < cnt; ++k) {
                int pkk = pk_h[base + k];                  // uniform -> s_load
                float wk = bcast_f(p, k);
                const __half* tp = ent16_cur + ((pkk & 0x3FFFF) << 6);
                const float*  wp = wt + (((pkk >> 18) & 15) << 6);
                acc += wk * __half2float(tp[lane]) * wp[lane];
            }
        }
        float agg = (l > 0.f) ? acc / l : 0.f;

        // --- + interact_mat^T @ user_emb  (nnz with col == e) ---
        // Descriptor (row, valbits) read at uniform address -> s_load_dwordx2;
        // no per-lane staging, no readlanes.
        int c1 = min(start[N_ENT + e + 1] - NE, NNZV);
        int c0 = max(min(start[N_ENT + e] - NE, c1), 0);
        {
            int k = c0;
            for (; k + 4 <= c1; k += 4) {
#pragma unroll
                for (int q = 0; q < 4; ++q) {
                    int2 t2 = rc[k + q];                   // uniform -> s_load
                    agg += __int_as_float(t2.y) *
                           __half2float(usr16_cur[(t2.x << 6) + lane]);
                }
            }
            for (; k < c1; ++k) {
                int2 t2 = rc[k];
                agg += __int_as_float(t2.y) *
                       __half2float(usr16_cur[(t2.x << 6) + lane]);
            }
        }

        // --- normalize + residual (+ next-hop sq from registers) ---
        float s = wave_sum(agg * agg);
        float y = agg / fmaxf(sqrtf(s), 1e-12f);
        int oi = (e << 6) + lane;
        if (!LAST) {
            ent16_next[oi] = __float2half(y);
            float y2 = y * y;
            float mine = 0.f;
#pragma unroll
            for (int rt = 0; rt < NREL9; ++rt) {
                float r = wt[(rt << 6) + lane];
                float sv = wave_sum(y2 * r * r);
                if (lane == rt) mine = sv;
            }
            if (lane < NREL9) sq_out[e * NREL9 + lane] = mine;
        }
        if (FIRST) out_ent[oi] = ent_res_base[oi] + y;
        else       out_ent[oi] += y;
    } else {
        // ================= user role: one wave per user ==================
        int u = __builtin_amdgcn_readfirstlane(((b - EG) * 256 + (int)threadIdx.x) >> 6);
        int s1 = min(start[2 * N_ENT + u + 1] - 2 * NE, NNZV);
        int s0 = max(min(start[2 * N_ENT + u] - 2 * NE, s1), 0);
        float accA = 0.f, accB = 0.f;
        {
            int k = s0;
            for (; k + 4 <= s1; k += 4) {
#pragma unroll
                for (int q = 0; q < 4; ++q) {
                    int2 t2 = cv[k + q];                   // uniform -> s_load
                    float prod = __int_as_float(t2.y) *
                                 __half2float(ent16_cur[(t2.x << 6) + lane]);
                    if (q & 1) accB += prod; else accA += prod;
                }
            }
            for (; k < s1; ++k) {
                int2 t2 = cv[k];
                accA += __int_as_float(t2.y) *
                        __half2float(ent16_cur[(t2.x << 6) + lane]);
            }
        }
        float acc = accA + accB;
        float s = wave_sum(acc * acc);
        float y = acc / fmaxf(sqrtf(s), 1e-12f);
        int oi = (u << 6) + lane;
        if (!LAST) usr16_next[oi] = __float2half(y);
        if (FIRST) out_usr[oi] = usr_res_base[oi] + y;
        else       out_usr[oi] += y;
    }
}

extern "C" void kernel_launch(void* const* d_in, const int* in_sizes, int n_in,
                              void* d_out, int out_size, void* d_ws, size_t ws_size,
                              hipStream_t stream)
{
    const float* user_emb   = (const float*)d_in[0];
    const float* entity_emb = (const float*)d_in[1];
    const float* wt         = (const float*)d_in[2];
    const float* inter_vals = (const float*)d_in[3];
    const int*   edge_index = (const int*)d_in[4];
    const int*   etype      = (const int*)d_in[5];
    const int*   inter_rows = (const int*)d_in[6];
    const int*   inter_cols = (const int*)d_in[7];
    const int* head  = edge_index;
    const int* tailp = edge_index + NE;

    // Workspace layout (~89 MB); every buffer written before read each call.
    __half* ent16_a = (__half*)d_ws;                         // N_ENT*64 halves
    __half* ent16_b = ent16_a + (size_t)N_ENT * CDIM;        // N_ENT*64
    __half* usr16_a = ent16_b + (size_t)N_ENT * CDIM;        // N_USR*64
    __half* usr16_b = usr16_a + (size_t)N_USR * CDIM;        // N_USR*64
    int2*  rc     = (int2*)(usr16_b + (size_t)N_USR * CDIM); // NNZ
    int2*  cv     = rc + NNZV;                               // NNZ
    int*   pk_h   = (int*)(cv + NNZV);                       // NE
    int*   cnt    = pk_h + NE;                               // NTOT
    int*   start  = cnt + NTOT;                              // NTOT+1
    int*   cursor = start + NTOT + 1;                        // NTOT+1
    int*   bsum   = cursor + NTOT + 1;                       // SCAN_B
    float* sq_a   = (float*)(bsum + SCAN_B);                 // N_ENT*9
    float* sq_b   = sq_a + (size_t)N_ENT * NREL9;            // N_ENT*9

    float* out_ent = (float*)d_out;
    float* out_usr = out_ent + (size_t)N_ENT * CDIM;

    // ---- CSR build + hop-1 prep (hist blocks FIRST for role mapping) ----
    hipMemsetAsync(cnt, 0, (size_t)NTOT * sizeof(int), stream);
    k_histprep<<<HISTB + EG + UCVT, 256, 0, stream>>>(
        head, inter_cols, inter_rows, cnt,
        entity_emb, user_emb, wt, ent16_a, usr16_a, sq_a);
    k_bsum<<<SCAN_B, 1024, 0, stream>>>(cnt, bsum);
    k_scan_small<<<1, 512, 0, stream>>>(bsum);
    k_scan_apply<<<SCAN_B, 1024, 0, stream>>>(cnt, bsum, start, cursor);
    k_scatter<<<NCHUNK * NXCD, 256, 0, stream>>>(
        head, tailp, etype, inter_rows, inter_cols, inter_vals,
        cursor, pk_h, rc, cv);

    // ---- hop 1: gather fp16_a; write fp16_b + sq_b; out = input + y1 ----
    k_hop<true, false><<<EG + UG, 256, 0, stream>>>(
        ent16_a, usr16_a, entity_emb, user_emb, wt, start, pk_h, sq_a, rc, cv,
        ent16_b, usr16_b, sq_b, out_ent, out_usr);

    // ---- hop 2: gather fp16_b; out += y2 ----
    k_hop<false, true><<<EG + UG, 256, 0, stream>>>(
        ent16_b, usr16_b, nullptr, nullptr, wt, start, pk_h, sq_b, rc, cv,
        nullptr, nullptr, nullptr, out_ent, out_usr);
}

// Round 10
// 625.453 us; speedup vs baseline: 1.1331x; 1.0766x over previous
//
#include <hip/hip_runtime.h>
#include <hip/hip_fp16.h>
#include <math.h>

#define N_ENT  150000
#define N_USR  60000
#define CDIM   64
#define NE     1000000
#define NNZV   1000000
#define NREL9  9                        // weight rows incl. np-wrap row 8
#define NTOT   (2 * N_ENT + N_USR)      // 360000 concatenated segment counters
#define TOTAL_ITEMS (NE + 2 * NNZV)     // 3000000 (scan sentinel)
#define SCAN_B ((NTOT + 1023) / 1024)   // 352 scan blocks

#define NXCD   8
#define H_PER  (N_ENT / NXCD)           // 18750 heads/cols per role
#define R_PER  (N_USR / NXCD)           // 7500 rows per role
#define EPB    2048                     // edges per chunk
#define NCHUNK ((NE + EPB - 1) / EPB)   // 489

#define EG (N_ENT / 4)                  // 37500 entity blocks (4 waves each)
#define UG (N_USR / 4)                  // 15000 user blocks
#define UCVT ((N_USR * CDIM / 2 + 255) / 256)  // 7500 usr-cvt blocks

// ---- LDS histogram geometry (atomic-free CSR counting) -------------------
#define SLICE_K 16384                   // counters per slice (64KB LDS)
#define SH 10                           // head slices  (10*16384 >= 150000)
#define SC 10                           // col slices
#define SR 4                            // row slices   (4*16384 >= 60000)
#define NSLICE (SH + SC + SR)           // 24
#define ESPLIT 8                        // edge-chunks per slice
#define ECH (NE / ESPLIT)               // 125000 (exact)
#define HIST_BLKS (NSLICE * ESPLIT)     // 192 blocks
#define RB ((NTOT + 255) / 256)         // 1407 reduce blocks

// ---- DPP wave reductions (VALU pipe, no LDS) ----------------------------
// rocPRIM warp_reduce_dpp pattern. bound_ctrl=true: OOR lanes contribute 0 —
// exact for sum, and for max of non-negative values.
template <int CTRL>
__device__ __forceinline__ float dpp_addf(float v) {
    int iv = __float_as_int(v);
    int x = __builtin_amdgcn_update_dpp(iv, iv, CTRL, 0xF, 0xF, true);
    return v + __int_as_float(x);
}
template <int CTRL>
__device__ __forceinline__ float dpp_maxf(float v) {
    int iv = __float_as_int(v);
    int x = __builtin_amdgcn_update_dpp(iv, iv, CTRL, 0xF, 0xF, true);
    return fmaxf(v, __int_as_float(x));
}
__device__ __forceinline__ float wave_sum(float v) {
    v = dpp_addf<0x111>(v);   // row_shr:1
    v = dpp_addf<0x112>(v);   // row_shr:2
    v = dpp_addf<0x114>(v);   // row_shr:4
    v = dpp_addf<0x118>(v);   // row_shr:8
    v = dpp_addf<0x142>(v);   // row_bcast:15
    v = dpp_addf<0x143>(v);   // row_bcast:31
    return __int_as_float(__builtin_amdgcn_readlane(__float_as_int(v), 63));
}
__device__ __forceinline__ float wave_max(float v) {
    v = dpp_maxf<0x111>(v);
    v = dpp_maxf<0x112>(v);
    v = dpp_maxf<0x114>(v);
    v = dpp_maxf<0x118>(v);
    v = dpp_maxf<0x142>(v);
    v = dpp_maxf<0x143>(v);
    return __int_as_float(__builtin_amdgcn_readlane(__float_as_int(v), 63));
}

__device__ __forceinline__ float bcast_f(float v, int l) { return __int_as_float(__builtin_amdgcn_readlane(__float_as_int(v), l)); }

// Block-wide exclusive scan (blockDim multiple of 64, <=1024). lds: >=16 ints.
__device__ __forceinline__ int block_excl_scan(int v, int* lds) {
    int lane = threadIdx.x & 63, wid = threadIdx.x >> 6;
    int incl = v;
#pragma unroll
    for (int o = 1; o < 64; o <<= 1) {
        int t = __shfl_up(incl, o, 64);
        if (lane >= o) incl += t;
    }
    if (lane == 63) lds[wid] = incl;
    __syncthreads();
    int nw = blockDim.x >> 6;
    if ((int)threadIdx.x < nw) {
        int s = lds[threadIdx.x];
        int si = s;
        for (int o = 1; o < nw; o <<= 1) {
            int t = __shfl_up(si, o, 64);
            if ((int)threadIdx.x >= o) si += t;
        }
        lds[threadIdx.x] = si - s;  // exclusive offset for this wave
    }
    __syncthreads();
    return incl - v + lds[wid];
}

// ---- Atomic-free histogram: block (sid, chunk) owns one 16K-counter slice
// in LDS, scans 1/8 of its key array, and flushes via PLAIN stores into a
// private per-block buffer. Zero global atomics (R9 finding: device atomics
// write through at 32B granules — 3M atomics cost ~94MB of HBM writes).
__global__ __launch_bounds__(256) void k_hist_lds(
    const int* __restrict__ head, const int* __restrict__ cols,
    const int* __restrict__ rows, int* __restrict__ priv)
{
    __shared__ int h[SLICE_K];
    int sid = blockIdx.x >> 3, chunk = blockIdx.x & (ESPLIT - 1);
    const int* key; int k0;
    if (sid < SH)            { key = head; k0 = sid * SLICE_K; }
    else if (sid < SH + SC)  { key = cols; k0 = (sid - SH) * SLICE_K; }
    else                     { key = rows; k0 = (sid - SH - SC) * SLICE_K; }
    for (int t = threadIdx.x; t < SLICE_K; t += 256) h[t] = 0;
    __syncthreads();
    const int4* key4 = (const int4*)(key + chunk * ECH);   // ECH % 4 == 0
    for (int i = threadIdx.x; i < ECH / 4; i += 256) {
        int4 k4 = key4[i];
        int a = k4.x - k0, b = k4.y - k0, c = k4.z - k0, d = k4.w - k0;
        if ((unsigned)a < (unsigned)SLICE_K) atomicAdd(&h[a], 1);
        if ((unsigned)b < (unsigned)SLICE_K) atomicAdd(&h[b], 1);
        if ((unsigned)c < (unsigned)SLICE_K) atomicAdd(&h[c], 1);
        if ((unsigned)d < (unsigned)SLICE_K) atomicAdd(&h[d], 1);
    }
    __syncthreads();
    int* dst = priv + (size_t)blockIdx.x * SLICE_K;
    for (int t = threadIdx.x; t < SLICE_K; t += 256) dst[t] = h[t];
}

// ---- Fused reduce + hop-1 prep: blocks [0,RB) sum the ESPLIT private
// histogram copies into cnt (fully written -> no memset needed);
// [RB,RB+EG) entity fp16 cvt + sq table; rest usr fp16 cvt.
__global__ __launch_bounds__(256) void k_prepreduce(
    const int* __restrict__ priv, int* __restrict__ cnt,
    const float* __restrict__ ent, const float* __restrict__ usr,
    const float* __restrict__ wt,
    __half* __restrict__ ent16, __half* __restrict__ usr16,
    float* __restrict__ sq)
{
    int b = blockIdx.x;
    if (b < RB) {
        int i = b * 256 + (int)threadIdx.x;
        if (i >= NTOT) return;
        int sid, local;
        if (i < N_ENT)          { sid = i >> 14;                    local = i & (SLICE_K - 1); }
        else if (i < 2 * N_ENT) { int j = i - N_ENT;     sid = SH + (j >> 14);      local = j & (SLICE_K - 1); }
        else                    { int j = i - 2 * N_ENT; sid = SH + SC + (j >> 14); local = j & (SLICE_K - 1); }
        const int* p = priv + (size_t)(sid * ESPLIT) * SLICE_K + local;
        int s = 0;
#pragma unroll
        for (int c = 0; c < ESPLIT; ++c) s += p[(size_t)c * SLICE_K];
        cnt[i] = s;
    } else if (b < RB + EG) {
        int e = ((b - RB) * 256 + (int)threadIdx.x) >> 6;
        int lane = threadIdx.x & 63;
        float own = ent[(e << 6) + lane];
        ent16[(e << 6) + lane] = __float2half(own);
        float o2 = own * own;
        float mine = 0.f;
#pragma unroll
        for (int rt = 0; rt < NREL9; ++rt) {
            float r = wt[(rt << 6) + lane];
            float s = wave_sum(o2 * r * r);
            if (lane == rt) mine = s;
        }
        if (lane < NREL9) sq[e * NREL9 + lane] = mine;
    } else {
        int i = (b - RB - EG) * 256 + (int)threadIdx.x;   // float2 index
        if (i < N_USR * CDIM / 2) {
            float2 v = ((const float2*)usr)[i];
            ((__half2*)usr16)[i] = __floats2half2_rn(v.x, v.y);
        }
    }
}

__global__ __launch_bounds__(1024) void k_bsum(
    const int* __restrict__ cnt, int* __restrict__ bsum)
{
    __shared__ int lds[16];
    int i = blockIdx.x * 1024 + threadIdx.x;
    float v = (i < NTOT) ? (float)cnt[i] : 0.f;
    float s = wave_sum(v);                 // exact: block total <= 3M < 2^24
    int lane = threadIdx.x & 63, wid = threadIdx.x >> 6;
    if (lane == 0) lds[wid] = (int)s;
    __syncthreads();
    if (threadIdx.x == 0) {
        int t = 0;
        for (int k = 0; k < 16; ++k) t += lds[k];
        bsum[blockIdx.x] = t;
    }
}

__global__ __launch_bounds__(512) void k_scan_small(int* __restrict__ bsum)
{
    __shared__ int lds[16];
    int i = threadIdx.x;
    int v = (i < SCAN_B) ? bsum[i] : 0;
    int e = block_excl_scan(v, lds);
    if (i < SCAN_B) bsum[i] = e;
}

// start[i] = exclusive prefix (immutable); start[NTOT] = sentinel.
__global__ __launch_bounds__(1024) void k_scan_apply(
    const int* __restrict__ cnt, const int* __restrict__ bsum,
    int* __restrict__ start, int* __restrict__ cursor)
{
    __shared__ int lds[16];
    int i = blockIdx.x * 1024 + threadIdx.x;
    int v = (i < NTOT) ? cnt[i] : 0;
    int e = block_excl_scan(v, lds) + bsum[blockIdx.x];
    if (i < NTOT) { start[i] = e; cursor[i] = e; }
    else if (i == NTOT) { start[i] = TOTAL_ITEMS; }
}

// Scatter payloads into segment-sorted arrays. XCD-localized (R0). Payload
// fields loaded CONDITIONALLY (tail/etype 1/8 of iters, vals ~1/4).
__global__ __launch_bounds__(256) void k_scatter(
    const int* __restrict__ head, const int* __restrict__ tail,
    const int* __restrict__ etype,
    const int* __restrict__ rows, const int* __restrict__ cols,
    const float* __restrict__ vals,
    int* __restrict__ cursor,
    int* __restrict__ pk_h,                  // tail | rt<<18, sorted by head
    int2* __restrict__ rc,                   // (row, valbits) sorted by col
    int2* __restrict__ cv)                   // (col, valbits) sorted by row
{
    int role  = blockIdx.x & (NXCD - 1);
    int chunk = blockIdx.x >> 3;
    int h0 = role * H_PER, h1 = h0 + H_PER;
    int r0 = role * R_PER, r1 = r0 + R_PER;
    int base = chunk * EPB;
    int end  = min(base + EPB, NE);
    for (int i = base + (int)threadIdx.x; i < end; i += 256) {
        int h = head[i];
        int c = cols[i];
        int r = rows[i];
        if (h >= h0 && h < h1) {
            int rt = etype[i] - 1;
            if (rt < 0) rt = 8;              // weight[-1] -> row 8 (np wrap)
            int p = atomicAdd(cursor + h, 1);
            if ((unsigned)p < (unsigned)NE) pk_h[p] = tail[i] | (rt << 18);
        }
        if (c >= h0 && c < h1) {
            int vb = __float_as_int(vals[i]);
            int p = atomicAdd(cursor + N_ENT + c, 1) - NE;
            if ((unsigned)p < (unsigned)NNZV) rc[p] = make_int2(r, vb);
        }
        if (r >= r0 && r < r1) {
            int vb = __float_as_int(vals[i]);
            int p = atomicAdd(cursor + 2 * N_ENT + r, 1) - 2 * NE;
            if ((unsigned)p < (unsigned)NNZV) cv[p] = make_int2(c, vb);
        }
    }
}

// ---- Fused per-hop kernel: blocks [0,EG) = entity role, rest = user. ----
// e/u hoisted to SGPR via readfirstlane -> segment bounds and descriptor
// addresses are provably wave-uniform -> rc/cv/pk_h broadcast reads become
// SMEM s_load (no VALU, no per-lane staging, no readlanes). The pk gather
// loop keeps exactly ONE readlane per edge (wk, computed per-lane by exp).
template <bool FIRST, bool LAST>
__global__ __launch_bounds__(256) void k_hop(
    const __half* __restrict__ ent16_cur, const __half* __restrict__ usr16_cur,
    const float* __restrict__ ent_res_base, const float* __restrict__ usr_res_base,
    const float* __restrict__ wt, const int* __restrict__ start,
    const int* __restrict__ pk_h, const float* __restrict__ sq_in,
    const int2* __restrict__ rc, const int2* __restrict__ cv,
    __half* __restrict__ ent16_next, __half* __restrict__ usr16_next,
    float* __restrict__ sq_out,
    float* __restrict__ out_ent, float* __restrict__ out_usr)
{
    int lane = threadIdx.x & 63;
    int b = blockIdx.x;

    if (b < EG) {
        // ================= entity role: one wave per entity ==============
        int e = __builtin_amdgcn_readfirstlane((b * 256 + (int)threadIdx.x) >> 6);

        // --- softmax-weighted neighbor aggregation, edges head == e ---
        int s1 = min(start[e + 1], NE);
        int s0 = min(start[e], s1);
        float m = 0.f, l = 0.f, acc = 0.f;    // att >= 0 so m=0 init exact
        for (int base = s0; base < s1; base += 64) {
            int j = base + lane;
            int cnt = min(64, s1 - base);
            float att = 0.f;
            if (j < s1) {                      // coalesced descriptor load
                int pk = pk_h[j];
                int t = pk & 0x3FFFF, rt = (pk >> 18) & 15;
                att = sq_in[e * NREL9 + rt] * sq_in[t * NREL9 + rt];
            }
            float mn = fmaxf(m, wave_max(att));
            float scale = __expf(m - mn);      // first chunk multiplies zeros
            float p = (j < s1) ? __expf(att - mn) : 0.f;
            l = l * scale + wave_sum(p);
            acc *= scale;
            m = mn;
            int k = 0;
            for (; k + 4 <= cnt; k += 4) {     // 4 independent gathers in flight
#pragma unroll
                for (int q = 0; q < 4; ++q) {
                    int pkk = pk_h[base + k + q];          // uniform -> s_load
                    float wk = bcast_f(p, k + q);
                    const __half* tp = ent16_cur + ((pkk & 0x3FFFF) << 6);
                    const float*  wp = wt + (((pkk >> 18) & 15) << 6);
                    acc += wk * __half2float(tp[lane]) * wp[lane];
                }
            }
            for (; k < cnt; ++k) {
                int pkk = pk_h[base + k];                  // uniform -> s_load
                float wk = bcast_f(p, k);
                const __half* tp = ent16_cur + ((pkk & 0x3FFFF) << 6);
                const float*  wp = wt + (((pkk >> 18) & 15) << 6);
                acc += wk * __half2float(tp[lane]) * wp[lane];
            }
        }
        float agg = (l > 0.f) ? acc / l : 0.f;

        // --- + interact_mat^T @ user_emb  (nnz with col == e) ---
        // Descriptor (row, valbits) read at uniform address -> s_load_dwordx2;
        // no per-lane staging, no readlanes.
        int c1 = min(start[N_ENT + e + 1] - NE, NNZV);
        int c0 = max(min(start[N_ENT + e] - NE, c1), 0);
        {
            int k = c0;
            for (; k + 4 <= c1; k += 4) {
#pragma unroll
                for (int q = 0; q < 4; ++q) {
                    int2 t2 = rc[k + q];                   // uniform -> s_load
                    agg += __int_as_float(t2.y) *
                           __half2float(usr16_cur[(t2.x << 6) + lane]);
                }
            }
            for (; k < c1; ++k) {
                int2 t2 = rc[k];
                agg += __int_as_float(t2.y) *
                       __half2float(usr16_cur[(t2.x << 6) + lane]);
            }
        }

        // --- normalize + residual (+ next-hop sq from registers) ---
        float s = wave_sum(agg * agg);
        float y = agg / fmaxf(sqrtf(s), 1e-12f);
        int oi = (e << 6) + lane;
        if (!LAST) {
            ent16_next[oi] = __float2half(y);
            float y2 = y * y;
            float mine = 0.f;
#pragma unroll
            for (int rt = 0; rt < NREL9; ++rt) {
                float r = wt[(rt << 6) + lane];
                float sv = wave_sum(y2 * r * r);
                if (lane == rt) mine = sv;
            }
            if (lane < NREL9) sq_out[e * NREL9 + lane] = mine;
        }
        if (FIRST) out_ent[oi] = ent_res_base[oi] + y;
        else       out_ent[oi] += y;
    } else {
        // ================= user role: one wave per user ==================
        int u = __builtin_amdgcn_readfirstlane(((b - EG) * 256 + (int)threadIdx.x) >> 6);
        int s1 = min(start[2 * N_ENT + u + 1] - 2 * NE, NNZV);
        int s0 = max(min(start[2 * N_ENT + u] - 2 * NE, s1), 0);
        float accA = 0.f, accB = 0.f;
        {
            int k = s0;
            for (; k + 4 <= s1; k += 4) {
#pragma unroll
                for (int q = 0; q < 4; ++q) {
                    int2 t2 = cv[k + q];                   // uniform -> s_load
                    float prod = __int_as_float(t2.y) *
                                 __half2float(ent16_cur[(t2.x << 6) + lane]);
                    if (q & 1) accB += prod; else accA += prod;
                }
            }
            for (; k < s1; ++k) {
                int2 t2 = cv[k];
                accA += __int_as_float(t2.y) *
                        __half2float(ent16_cur[(t2.x << 6) + lane]);
            }
        }
        float acc = accA + accB;
        float s = wave_sum(acc * acc);
        float y = acc / fmaxf(sqrtf(s), 1e-12f);
        int oi = (u << 6) + lane;
        if (!LAST) usr16_next[oi] = __float2half(y);
        if (FIRST) out_usr[oi] = usr_res_base[oi] + y;
        else       out_usr[oi] += y;
    }
}

extern "C" void kernel_launch(void* const* d_in, const int* in_sizes, int n_in,
                              void* d_out, int out_size, void* d_ws, size_t ws_size,
                              hipStream_t stream)
{
    const float* user_emb   = (const float*)d_in[0];
    const float* entity_emb = (const float*)d_in[1];
    const float* wt         = (const float*)d_in[2];
    const float* inter_vals = (const float*)d_in[3];
    const int*   edge_index = (const int*)d_in[4];
    const int*   etype      = (const int*)d_in[5];
    const int*   inter_rows = (const int*)d_in[6];
    const int*   inter_cols = (const int*)d_in[7];
    const int* head  = edge_index;
    const int* tailp = edge_index + NE;

    // Workspace layout (~85 MB); every buffer written before read each call.
    __half* ent16_a = (__half*)d_ws;                         // N_ENT*64 halves
    __half* ent16_b = ent16_a + (size_t)N_ENT * CDIM;        // N_ENT*64
    __half* usr16_a = ent16_b + (size_t)N_ENT * CDIM;        // N_USR*64
    __half* usr16_b = usr16_a + (size_t)N_USR * CDIM;        // N_USR*64
    int2*  rc     = (int2*)(usr16_b + (size_t)N_USR * CDIM); // NNZ
    int2*  cv     = rc + NNZV;                               // NNZ
    int*   pk_h   = (int*)(cv + NNZV);                       // NE
    int*   cnt    = pk_h + NE;                               // NTOT
    int*   start  = cnt + NTOT;                              // NTOT+1
    int*   cursor = start + NTOT + 1;                        // NTOT+1
    int*   bsum   = cursor + NTOT + 1;                       // SCAN_B
    float* sq_a   = (float*)(bsum + SCAN_B);                 // N_ENT*9
    float* sq_b   = sq_a + (size_t)N_ENT * NREL9;            // N_ENT*9
    // priv histograms (12.6MB) alias ent16_b (19.2MB): priv dies after
    // k_prepreduce; ent16_b first written by hop 1 (strictly later).
    int* priv = (int*)ent16_b;                               // HIST_BLKS*SLICE_K

    float* out_ent = (float*)d_out;
    float* out_usr = out_ent + (size_t)N_ENT * CDIM;

    // ---- CSR build (atomic-free hist) + hop-1 prep ----
    k_hist_lds<<<HIST_BLKS, 256, 0, stream>>>(head, inter_cols, inter_rows, priv);
    k_prepreduce<<<RB + EG + UCVT, 256, 0, stream>>>(
        priv, cnt, entity_emb, user_emb, wt, ent16_a, usr16_a, sq_a);
    k_bsum<<<SCAN_B, 1024, 0, stream>>>(cnt, bsum);
    k_scan_small<<<1, 512, 0, stream>>>(bsum);
    k_scan_apply<<<SCAN_B, 1024, 0, stream>>>(cnt, bsum, start, cursor);
    k_scatter<<<NCHUNK * NXCD, 256, 0, stream>>>(
        head, tailp, etype, inter_rows, inter_cols, inter_vals,
        cursor, pk_h, rc, cv);

    // ---- hop 1: gather fp16_a; write fp16_b + sq_b; out = input + y1 ----
    k_hop<true, false><<<EG + UG, 256, 0, stream>>>(
        ent16_a, usr16_a, entity_emb, user_emb, wt, start, pk_h, sq_a, rc, cv,
        ent16_b, usr16_b, sq_b, out_ent, out_usr);

    // ---- hop 2: gather fp16_b; out += y2 ----
    k_hop<false, true><<<EG + UG, 256, 0, stream>>>(
        ent16_b, usr16_b, nullptr, nullptr, wt, start, pk_h, sq_b, rc, cv,
        nullptr, nullptr, nullptr, out_ent, out_usr);
}